// Round 1
// 1455.865 us; speedup vs baseline: 1.7623x; 1.7623x over previous
//
#include <hip/hip_runtime.h>
#include <hip/hip_bf16.h>

typedef __hip_bfloat16 bf16;

#define KK 512    // kept tokens (epoch=20 -> ratio 0.5, K = 1024/2)

// ---- static device scratch (outside all harness buffers) ----
__device__ float g_xm[1048576];        // (B,C,H,W) router mean
__device__ float g_h1[262144];         // (B,32,H,W) router hidden
__device__ float g_scal[4096];         // (B,K) STE scale
__device__ int   g_idx[4096];          // (B,K) selected spatial indices (sorted)
__device__ float g_xg[4194304];        // (B,K,T,C) gathered+scaled tokens (dense)
__device__ float g_zs[4194304];        // (B*T, K, C) mamba output
__device__ float g_qkv[12582912];      // (B*T, K, 384) attn qkv
__device__ float g_o[4194304];         // (B*T, K, C) attn context
// new mamba pipeline scratch
__device__ float g_zn[4194304];        // (B*K*T, 128) rmsnormed tokens
__device__ float g_xz[16777216];       // (B*K*T, 512) in_proj output
__device__ float g_y[8388608];         // (B*K*T, 256) gated scan output
__device__ float g_wint[65536];        // in_proj_w transposed (128 x 512)
__device__ float g_woutt[32768];       // out_proj_w transposed (256 x 128)

__device__ __forceinline__ float b2f(bf16 v) { return __bfloat162float(v); }

// ---------------- P1: init tables with valid defaults (defensive) ----------------
__global__ void t_init(int dummy) {
    int e = blockIdx.x * 256 + threadIdx.x;
    if (e < 4096) { g_scal[e] = 1.0f; g_idx[e] = e & 511; }
}

// ---------------- K1: xm = mean over T of x_in ----------------
__global__ void k_mean(const float* __restrict__ x) {
    int id = blockIdx.x * 256 + threadIdx.x;      // < 8*128*1024
    int n = id & 1023;
    int c = (id >> 10) & 127;
    int b = id >> 17;
    float s = 0.f;
#pragma unroll
    for (int t = 0; t < 8; ++t)
        s += x[(((b * 8 + t) * 128 + c) << 10) + n];
    g_xm[id] = s * 0.125f;
}

// ---------------- K2: 3x3 conv 128->32 + bias + LeakyReLU ----------------
__global__ void k_router_conv(const float* __restrict__ w, const float* __restrict__ bias) {
    int id = blockIdx.x * 256 + threadIdx.x;      // < 8*32*1024
    int x = id & 31;
    int y = (id >> 5) & 31;
    int oc = (id >> 10) & 31;
    int b = id >> 15;
    const float* xb = g_xm + b * 131072;
    float acc = bias[oc];
    for (int ic = 0; ic < 128; ++ic) {
        const float* wr = w + (oc * 128 + ic) * 9;
        const float* xr = xb + ic * 1024;
#pragma unroll
        for (int ky = 0; ky < 3; ++ky) {
            int yy = y + ky - 1;
            if (yy < 0 || yy > 31) continue;
#pragma unroll
            for (int kx = 0; kx < 3; ++kx) {
                int xx = x + kx - 1;
                if (xx < 0 || xx > 31) continue;
                acc += xr[yy * 32 + xx] * wr[ky * 3 + kx];
            }
        }
    }
    g_h1[id] = acc >= 0.f ? acc : 0.01f * acc;
}

// -------- K3: 1x1 conv + sigmoid + exact top-k(512) into g_idx/g_scal --------
__global__ __launch_bounds__(1024) void k_topk(const float* __restrict__ r2w,
                                               const float* __restrict__ r2b) {
    __shared__ float sc[1024];
    __shared__ int flg[1024];
    int b = blockIdx.x;
    int n = threadIdx.x;
    float a = r2b[0];
#pragma unroll
    for (int ic = 0; ic < 32; ++ic)
        a += g_h1[b * 32768 + ic * 1024 + n] * r2w[ic];
    float s = 1.f / (1.f + expf(-a));
    sc[n] = s;
    __syncthreads();
    // jax top_k tie-breaking (lower index wins) -> rank is a permutation of 0..1023
    int rank = 0;
    for (int j = 0; j < 1024; ++j) {
        float v = sc[j];
        rank += (v > s) || (v == s && j < n);
    }
    int sel = rank < KK ? 1 : 0;
    flg[n] = sel;
    __syncthreads();
    for (int d = 1; d < 1024; d <<= 1) {          // inclusive Hillis-Steele scan
        int add = (n >= d) ? flg[n - d] : 0;
        __syncthreads();
        flg[n] += add;
        __syncthreads();
    }
    if (sel) {
        int pos = (flg[n] - 1) & 511;
        g_idx[b * KK + pos] = n;
        g_scal[b * KK + pos] = s / (s + 1e-6f);
    }
}

// ---------------- K4: out = x_in everywhere (unselected final) ----------------
__global__ void k_copy(const float4* __restrict__ src, float4* __restrict__ dst) {
    int id = blockIdx.x * 256 + threadIdx.x;      // 2,097,152 float4
    dst[id] = src[id];
}

// ------ K4b: coalesced gather: g_xg[(b,k),(t,c)] = x_in[b,t,c,n(k)] * scl(k) ------
__global__ __launch_bounds__(256) void k_gather(const float* __restrict__ x) {
    __shared__ float lds[16][1024];               // 64 KB
    int blk = blockIdx.x;                         // 512 = 8b * 8t * 8cc
    int cchunk = blk & 7;
    int t = (blk >> 3) & 7;
    int b = blk >> 6;
    int c0 = cchunk * 16;
    int tid = threadIdx.x;
    const float* src = x + ((size_t)(b * 8 + t) * 128 + c0) * 1024;
#pragma unroll
    for (int r = 0; r < 64; ++r) {
        int e = tid + r * 256;                    // 16384
        lds[e >> 10][e & 1023] = src[e];
    }
    __syncthreads();
#pragma unroll
    for (int half = 0; half < 2; ++half) {
        int k = tid + half * 256;
        int n = g_idx[b * KK + k] & 1023;
        float scl = fminf(fmaxf(g_scal[b * KK + k], 0.f), 1.f);
        float* dst = g_xg + ((size_t)(b * 512 + k) * 8 + t) * 128 + c0;
#pragma unroll
        for (int cc = 0; cc < 16; ++cc)
            dst[cc] = lds[cc][n] * scl;
    }
}

// ---------------- K_wt: one-time weight transposes for the GEMMs ----------------
__global__ void k_wt(const float* __restrict__ w_in, const float* __restrict__ w_out) {
    int e = blockIdx.x * 256 + threadIdx.x;       // grid covers 65536
    if (e < 65536) { int j = e >> 7; int c = e & 127; g_wint[c * 512 + j] = w_in[e]; }
    if (e < 32768) { int i = e >> 8; int c = e & 255; g_woutt[c * 128 + i] = w_out[e]; }
}

// ---------------- K_rms: rmsnorm rows of g_xg -> g_zn ----------------
__global__ __launch_bounds__(256) void k_rms(const float* __restrict__ w) {
    int r = blockIdx.x * 4 + (threadIdx.x >> 6);  // one wave per row
    int l = threadIdx.x & 63;
    const float* src = g_xg + (size_t)r * 128;
    float2 v = *(const float2*)(src + l * 2);
    float ss = v.x * v.x + v.y * v.y;
#pragma unroll
    for (int off = 32; off; off >>= 1) ss += __shfl_down(ss, off, 64);
    ss = __shfl(ss, 0, 64);
    float rstd = rsqrtf(ss * (1.f / 128.f) + 1e-5f);
    float* dst = g_zn + (size_t)r * 128;
    dst[l * 2]     = v.x * rstd * w[l * 2];
    dst[l * 2 + 1] = v.y * rstd * w[l * 2 + 1];
}

// ---------------- K_gemm: fp32 tiled GEMM, tile 128x128, K-chunks of 32 ----------------
// MODE 0: g_xz(32768x512)  = g_zn(32768x128) @ g_wint  (in_proj)
// MODE 1: g_zs(scattered)  = g_y (32768x256) @ g_woutt (out_proj, (b,k,t)->(b,t,k) scatter)
template<int KTOT, int NTOT, int MODE>
__global__ __launch_bounds__(256, 2) void k_gemm() {
    __shared__ float At[32][132];                 // transposed A chunk, pad to kill bank conflicts
    __shared__ float Bs[32][128];                 // B^T chunk (pre-transposed in global), linear
    const float* A  = (MODE == 0) ? g_zn : g_y;
    const float* Bt = (MODE == 0) ? g_wint : g_woutt;
    float* Cc       = (MODE == 0) ? g_xz : g_zs;
    const int NT = NTOT / 128;
    int mt = blockIdx.x / NT;
    int nt = blockIdx.x % NT;
    int tid = threadIdx.x;
    int mi = tid & 15;                            // row group: rows {4mi..4mi+3} u {64+4mi..}
    int ni = tid >> 4;                            // col group: cols {4ni..4ni+3} u {64+4ni..}

    float4 acc[2][2][4];
#pragma unroll
    for (int a = 0; a < 2; ++a)
#pragma unroll
        for (int bq = 0; bq < 2; ++bq)
#pragma unroll
            for (int rr = 0; rr < 4; ++rr)
                acc[a][bq][rr] = make_float4(0.f, 0.f, 0.f, 0.f);

    for (int kc = 0; kc < KTOT; kc += 32) {
        // stage A (128 rows x 32 k) transposed into LDS
#pragma unroll
        for (int i = 0; i < 16; ++i) {
            int e = tid + i * 256;                // 4096
            int m = e >> 5, c = e & 31;
            At[c][m] = A[(size_t)(mt * 128 + m) * KTOT + kc + c];
        }
        // stage B^T (32 k x 128 n) linear
#pragma unroll
        for (int i = 0; i < 16; ++i) {
            int e = tid + i * 256;                // 4096
            int c = e >> 7, n = e & 127;
            Bs[c][n] = Bt[(size_t)(kc + c) * NTOT + nt * 128 + n];
        }
        __syncthreads();
#pragma unroll 8
        for (int c = 0; c < 32; ++c) {
            float4 a0 = *(const float4*)&At[c][4 * mi];
            float4 a1 = *(const float4*)&At[c][64 + 4 * mi];
            float4 b0 = *(const float4*)&Bs[c][4 * ni];
            float4 b1 = *(const float4*)&Bs[c][64 + 4 * ni];
            float ar[8] = {a0.x, a0.y, a0.z, a0.w, a1.x, a1.y, a1.z, a1.w};
#pragma unroll
            for (int r = 0; r < 8; ++r) {
                int a = r >> 2, rr = r & 3;
                acc[a][0][rr].x += ar[r] * b0.x; acc[a][0][rr].y += ar[r] * b0.y;
                acc[a][0][rr].z += ar[r] * b0.z; acc[a][0][rr].w += ar[r] * b0.w;
                acc[a][1][rr].x += ar[r] * b1.x; acc[a][1][rr].y += ar[r] * b1.y;
                acc[a][1][rr].z += ar[r] * b1.z; acc[a][1][rr].w += ar[r] * b1.w;
            }
        }
        __syncthreads();
    }

    // epilogue
#pragma unroll
    for (int a = 0; a < 2; ++a)
#pragma unroll
        for (int rr = 0; rr < 4; ++rr) {
            int r = mt * 128 + a * 64 + 4 * mi + rr;
#pragma unroll
            for (int bq = 0; bq < 2; ++bq) {
                int col = nt * 128 + bq * 64 + 4 * ni;
                if (MODE == 0) {
                    *(float4*)&Cc[(size_t)r * NTOT + col] = acc[a][bq][rr];
                } else {
                    int bb = r >> 12;             // r = (bb*512 + k)*8 + t
                    int k = (r >> 3) & 511;
                    int t = r & 7;
                    *(float4*)&Cc[((size_t)(bb * 8 + t) * 512 + k) * 128 + col] = acc[a][bq][rr];
                }
            }
        }
}

// ---------------- K_scan: conv + x_proj + dt_proj + selective scan + gate ----------------
__global__ __launch_bounds__(256, 2) void k_scan(const float* __restrict__ w_xp,
                        const float* __restrict__ conv_w, const float* __restrict__ conv_b,
                        const float* __restrict__ w_dt, const float* __restrict__ b_dt,
                        const float* __restrict__ A_log, const float* __restrict__ Dp) {
    __shared__ float xcv[8][256];
    __shared__ float xdbl[8][40];
    int tok = blockIdx.x;                         // b*512 + k
    int tid = threadIdx.x;
    const float* xzr = g_xz + (size_t)tok * 8 * 512;

    {   // causal depthwise conv (k=4, left pad 3) + bias + silu; coalesced global col reads
        int d = tid;
        float w0 = conv_w[d * 4 + 0], w1 = conv_w[d * 4 + 1];
        float w2 = conv_w[d * 4 + 2], w3 = conv_w[d * 4 + 3];
        float cb = conv_b[d];
        float x0 = 0.f, x1 = 0.f, x2 = 0.f;
#pragma unroll
        for (int t = 0; t < 8; ++t) {
            float x3 = xzr[t * 512 + d];
            float v = x0 * w0 + x1 * w1 + x2 * w2 + x3 * w3 + cb;
            v = v / (1.f + expf(-v));
            xcv[t][d] = v;
            x0 = x1; x1 = x2; x2 = x3;
        }
    }
    __syncthreads();

#pragma unroll
    for (int r = 0; r < 2; ++r) {                 // x_proj (8,256)@(40,256)^T
        int e = tid + r * 256;
        if (e < 320) {
            int t = e / 40, j = e % 40;
            const float4* wr = (const float4*)(w_xp + j * 256);
            const float4* xr = (const float4*)xcv[t];
            float acc = 0.f;
#pragma unroll 8
            for (int c = 0; c < 64; ++c) {
                float4 w4 = wr[c], x4 = xr[c];
                acc += x4.x * w4.x + x4.y * w4.y + x4.z * w4.z + x4.w * w4.w;
            }
            xdbl[t][j] = acc;
        }
    }
    __syncthreads();

    {   // dt_proj + softplus + selective scan, 16 states in registers
        int d = tid;
        float wdt[8];
#pragma unroll
        for (int r = 0; r < 8; ++r) wdt[r] = w_dt[d * 8 + r];
        float bdt = b_dt[d];
        float Av[16], h[16];
#pragma unroll
        for (int s = 0; s < 16; ++s) { Av[s] = -expf(A_log[d * 16 + s]); h[s] = 0.f; }
        float Dd = Dp[d];
        float* yr = g_y + (size_t)tok * 8 * 256;
#pragma unroll
        for (int t = 0; t < 8; ++t) {
            float dtv = bdt;
#pragma unroll
            for (int r = 0; r < 8; ++r) dtv += xdbl[t][r] * wdt[r];
            dtv = dtv > 20.f ? dtv : logf(1.f + expf(dtv));
            float u = xcv[t][d];
            float db = dtv * u;
            float y = 0.f;
#pragma unroll
            for (int s = 0; s < 16; ++s) {
                h[s] = h[s] * expf(dtv * Av[s]) + db * xdbl[t][8 + s];
                y += h[s] * xdbl[t][24 + s];
            }
            y += u * Dd;
            float zg = xzr[t * 512 + 256 + d];
            y *= zg / (1.f + expf(-zg));
            yr[t * 256 + d] = y;
        }
    }
}

// ---------------- K6: qkv projection, 32 tokens per block ----------------
__global__ __launch_bounds__(256) void k_qkv(const float* __restrict__ wi,
                                             const float* __restrict__ bi) {
    __shared__ float zr[32][128];                 // 16 KB
    int tok0 = blockIdx.x * 32;                   // 1024 blocks
    int tid = threadIdx.x;
#pragma unroll
    for (int r = 0; r < 16; ++r) {
        int e = tid + r * 256;
        zr[e >> 7][e & 127] = g_zs[(size_t)tok0 * 128 + e];
    }
    __syncthreads();
#pragma unroll
    for (int pass = 0; pass < 2; ++pass) {
        int j = tid + pass * 256;
        if (j < 384) {
            const float* wr = wi + j * 128;
            float bv = bi[j];
            float acc[32];
#pragma unroll
            for (int t = 0; t < 32; ++t) acc[t] = bv;
            for (int c = 0; c < 128; ++c) {
                float wv = wr[c];
#pragma unroll
                for (int t = 0; t < 32; ++t) acc[t] += zr[t][c] * wv;
            }
#pragma unroll
            for (int t = 0; t < 32; ++t)
                g_qkv[(size_t)(tok0 + t) * 384 + j] = acc[t];
        }
    }
}

// ---------------- K7: attention per (bt, head); K/V bf16 in LDS ----------------
__global__ __launch_bounds__(512) void k_attn2() {
    __shared__ bf16 kb[512][32];
    __shared__ bf16 vb[512][32];
    int bt = blockIdx.x >> 2;
    int h = blockIdx.x & 3;
    int tid = threadIdx.x;                        // one q token per thread
    const float* Q = g_qkv + (size_t)bt * 512 * 384;
    const float rs = 0.17677669529663687f;        // 1/sqrt(32)

#pragma unroll
    for (int r = 0; r < 32; ++r) {
        int e = tid + r * 512;                    // 16384 = 512 tok × 32 col
        int tok = e >> 5, c = e & 31;
        kb[tok][c] = __float2bfloat16(Q[tok * 384 + 128 + h * 32 + c]);
        vb[tok][c] = __float2bfloat16(Q[tok * 384 + 256 + h * 32 + c]);
    }
    __syncthreads();

    float qv[32];
#pragma unroll
    for (int c = 0; c < 32; ++c) qv[c] = Q[tid * 384 + h * 32 + c] * rs;

    float m = -1e30f, l = 0.f, acc[32];
#pragma unroll
    for (int c = 0; c < 32; ++c) acc[c] = 0.f;
    for (int kk = 0; kk < 512; ++kk) {
        float s = 0.f;
#pragma unroll
        for (int c = 0; c < 32; ++c) s += qv[c] * b2f(kb[kk][c]);
        float mn = fmaxf(m, s);
        float rsc = expf(m - mn);
        float e2 = expf(s - mn);
        l = l * rsc + e2;
#pragma unroll
        for (int c = 0; c < 32; ++c) acc[c] = acc[c] * rsc + e2 * b2f(vb[kk][c]);
        m = mn;
    }
    float inv = 1.f / l;
    float* orow = g_o + ((size_t)bt * 512 + tid) * 128 + h * 32;
#pragma unroll
    for (int c = 0; c < 32; ++c) orow[c] = acc[c] * inv;
}

// ------- K8: out_proj + residual + LayerNorm + scatter (fp32 d_out) -------
__global__ __launch_bounds__(128) void k_final(const float* __restrict__ x_in,
                       float* __restrict__ out,
                       const float* __restrict__ wo, const float* __restrict__ bo,
                       const float* __restrict__ ln_w, const float* __restrict__ ln_b) {
    __shared__ float orow[128];
    __shared__ float sh[4];
    int tk = blockIdx.x;                          // bt*512 + k
    int bt = tk >> 9, k = tk & 511;
    int b = bt >> 3;
    int i = threadIdx.x;                          // 128 threads
    orow[i] = g_o[(size_t)tk * 128 + i];
    __syncthreads();
    const float* wr = wo + i * 128;
    float acc = bo[i];
    for (int j = 0; j < 128; ++j) acc += orow[j] * wr[j];
    float xi = g_zs[(size_t)tk * 128 + i] + acc;
    float s1 = xi, s2 = xi * xi;
#pragma unroll
    for (int off = 32; off; off >>= 1) {
        s1 += __shfl_down(s1, off, 64);
        s2 += __shfl_down(s2, off, 64);
    }
    if ((i & 63) == 0) { sh[(i >> 6) * 2] = s1; sh[(i >> 6) * 2 + 1] = s2; }
    __syncthreads();
    float mu = (sh[0] + sh[2]) * (1.f / 128.f);
    float var = (sh[1] + sh[3]) * (1.f / 128.f) - mu * mu;
    float yo = (xi - mu) * rsqrtf(fmaxf(var, 0.f) + 1e-5f) * ln_w[i] + ln_b[i];
    int n = g_idx[b * KK + k] & 1023;
    size_t oi = (((size_t)(bt * 128 + i)) << 10) + n;
    out[oi] = x_in[oi] + yo;
}

extern "C" void kernel_launch(void* const* d_in, const int* in_sizes, int n_in,
                              void* d_out, int out_size, void* d_ws, size_t ws_size,
                              hipStream_t stream) {
    const float* x_in      = (const float*)d_in[0];
    const float* norm1_w   = (const float*)d_in[1];
    const float* in_proj_w = (const float*)d_in[2];
    const float* conv1d_w  = (const float*)d_in[3];
    const float* conv1d_b  = (const float*)d_in[4];
    const float* x_proj_w  = (const float*)d_in[5];
    const float* dt_proj_w = (const float*)d_in[6];
    const float* dt_proj_b = (const float*)d_in[7];
    const float* A_log     = (const float*)d_in[8];
    const float* Dp        = (const float*)d_in[9];
    const float* out_proj_w= (const float*)d_in[10];
    const float* r1_w      = (const float*)d_in[11];
    const float* r1_b      = (const float*)d_in[12];
    const float* r2_w      = (const float*)d_in[13];
    const float* r2_b      = (const float*)d_in[14];
    const float* attn_in_w = (const float*)d_in[15];
    const float* attn_in_b = (const float*)d_in[16];
    const float* attn_out_w= (const float*)d_in[17];
    const float* attn_out_b= (const float*)d_in[18];
    const float* ln_w      = (const float*)d_in[19];
    const float* ln_b      = (const float*)d_in[20];
    // d_in[21]: current_epoch == 20 (static) -> ratio 0.5 -> K = 512

    float* out = (float*)d_out;

    t_init<<<16, 256, 0, stream>>>(0);
    k_mean<<<4096, 256, 0, stream>>>(x_in);
    k_router_conv<<<1024, 256, 0, stream>>>(r1_w, r1_b);
    k_topk<<<8, 1024, 0, stream>>>(r2_w, r2_b);
    k_copy<<<8192, 256, 0, stream>>>((const float4*)x_in, (float4*)d_out);
    k_gather<<<512, 256, 0, stream>>>(x_in);
    k_wt<<<256, 256, 0, stream>>>(in_proj_w, out_proj_w);
    k_rms<<<8192, 256, 0, stream>>>(norm1_w);
    k_gemm<128, 512, 0><<<1024, 256, 0, stream>>>();   // in_proj
    k_scan<<<4096, 256, 0, stream>>>(x_proj_w, conv1d_w, conv1d_b,
                                     dt_proj_w, dt_proj_b, A_log, Dp);
    k_gemm<256, 128, 1><<<256, 256, 0, stream>>>();    // out_proj (+ layout scatter)
    k_qkv<<<1024, 256, 0, stream>>>(attn_in_w, attn_in_b);
    k_attn2<<<256, 512, 0, stream>>>();
    k_final<<<32768, 128, 0, stream>>>(x_in, out, attn_out_w, attn_out_b, ln_w, ln_b);
}

// Round 2
// 1153.714 us; speedup vs baseline: 2.2238x; 1.2619x over previous
//
#include <hip/hip_runtime.h>
#include <hip/hip_bf16.h>

typedef __hip_bfloat16 bf16;
typedef __attribute__((ext_vector_type(8))) short short8;
typedef __attribute__((ext_vector_type(4))) float f32x4;

#define KK 512    // kept tokens (epoch=20 -> ratio 0.5, K = 1024/2)

// ---- static device scratch (outside all harness buffers) ----
__device__ float g_xm[1048576];        // (B,C,H,W) router mean
__device__ float g_h1[262144];         // (B,32,H,W) router hidden
__device__ float g_scal[4096];         // (B,K) STE scale
__device__ int   g_idx[4096];          // (B,K) selected spatial indices (sorted)
__device__ float g_xg[4194304];        // (B,K,T,C) gathered+scaled tokens (dense)
__device__ float g_zs[4194304];        // (B*T, K, C) mamba output
__device__ float g_qkv[12582912];      // (B*T, K, 384) attn qkv
__device__ float g_o[4194304];         // (B*T, K, C) attn context
// mamba pipeline scratch
__device__ float g_zn[4194304];        // (B*K*T, 128) rmsnormed tokens
__device__ float g_xz[16777216];       // (B*K*T, 512) in_proj output
__device__ float g_y[8388608];         // (B*K*T, 256) gated scan output
__device__ float g_wint[65536];        // in_proj_w transposed (128 x 512)
__device__ float g_woutt[32768];       // out_proj_w transposed (256 x 128)

__device__ __forceinline__ float b2f(bf16 v) { return __bfloat162float(v); }

// round-to-nearest-even f32 -> bf16 bits
__device__ __forceinline__ ushort f2bu(float f) {
    union { float f; unsigned u; } v; v.f = f;
    unsigned r = v.u + 0x7fffu + ((v.u >> 16) & 1u);
    return (ushort)(r >> 16);
}

union U8 { short8 v; ushort u[8]; };

// ---------------- P1: init tables with valid defaults (defensive) ----------------
__global__ void t_init(int dummy) {
    int e = blockIdx.x * 256 + threadIdx.x;
    if (e < 4096) { g_scal[e] = 1.0f; g_idx[e] = e & 511; }
}

// ---------------- K1: xm = mean over T of x_in ----------------
__global__ void k_mean(const float* __restrict__ x) {
    int id = blockIdx.x * 256 + threadIdx.x;      // < 8*128*1024
    int n = id & 1023;
    int c = (id >> 10) & 127;
    int b = id >> 17;
    float s = 0.f;
#pragma unroll
    for (int t = 0; t < 8; ++t)
        s += x[(((b * 8 + t) * 128 + c) << 10) + n];
    g_xm[id] = s * 0.125f;
}

// ---------------- K2: 3x3 conv 128->32 + bias + LeakyReLU ----------------
__global__ void k_router_conv(const float* __restrict__ w, const float* __restrict__ bias) {
    int id = blockIdx.x * 256 + threadIdx.x;      // < 8*32*1024
    int x = id & 31;
    int y = (id >> 5) & 31;
    int oc = (id >> 10) & 31;
    int b = id >> 15;
    const float* xb = g_xm + b * 131072;
    float acc = bias[oc];
    for (int ic = 0; ic < 128; ++ic) {
        const float* wr = w + (oc * 128 + ic) * 9;
        const float* xr = xb + ic * 1024;
#pragma unroll
        for (int ky = 0; ky < 3; ++ky) {
            int yy = y + ky - 1;
            if (yy < 0 || yy > 31) continue;
#pragma unroll
            for (int kx = 0; kx < 3; ++kx) {
                int xx = x + kx - 1;
                if (xx < 0 || xx > 31) continue;
                acc += xr[yy * 32 + xx] * wr[ky * 3 + kx];
            }
        }
    }
    g_h1[id] = acc >= 0.f ? acc : 0.01f * acc;
}

// -------- K3: 1x1 conv + sigmoid + exact top-k(512) into g_idx/g_scal --------
__global__ __launch_bounds__(1024) void k_topk(const float* __restrict__ r2w,
                                               const float* __restrict__ r2b) {
    __shared__ float sc[1024];
    __shared__ int flg[1024];
    int b = blockIdx.x;
    int n = threadIdx.x;
    float a = r2b[0];
#pragma unroll
    for (int ic = 0; ic < 32; ++ic)
        a += g_h1[b * 32768 + ic * 1024 + n] * r2w[ic];
    float s = 1.f / (1.f + expf(-a));
    sc[n] = s;
    __syncthreads();
    // jax top_k tie-breaking (lower index wins) -> rank is a permutation of 0..1023
    int rank = 0;
    for (int j = 0; j < 1024; ++j) {
        float v = sc[j];
        rank += (v > s) || (v == s && j < n);
    }
    int sel = rank < KK ? 1 : 0;
    flg[n] = sel;
    __syncthreads();
    for (int d = 1; d < 1024; d <<= 1) {          // inclusive Hillis-Steele scan
        int add = (n >= d) ? flg[n - d] : 0;
        __syncthreads();
        flg[n] += add;
        __syncthreads();
    }
    if (sel) {
        int pos = (flg[n] - 1) & 511;
        g_idx[b * KK + pos] = n;
        g_scal[b * KK + pos] = s / (s + 1e-6f);
    }
}

// ---------------- K4: out = x_in everywhere (unselected final) ----------------
__global__ void k_copy(const float4* __restrict__ src, float4* __restrict__ dst) {
    int id = blockIdx.x * 256 + threadIdx.x;      // 2,097,152 float4
    dst[id] = src[id];
}

// ------ K4b: coalesced gather: g_xg[(b,k),(t,c)] = x_in[b,t,c,n(k)] * scl(k) ------
__global__ __launch_bounds__(256) void k_gather(const float* __restrict__ x) {
    __shared__ float lds[16][1024];               // 64 KB
    int blk = blockIdx.x;                         // 512 = 8b * 8t * 8cc
    int cchunk = blk & 7;
    int t = (blk >> 3) & 7;
    int b = blk >> 6;
    int c0 = cchunk * 16;
    int tid = threadIdx.x;
    const float* src = x + ((size_t)(b * 8 + t) * 128 + c0) * 1024;
#pragma unroll
    for (int r = 0; r < 64; ++r) {
        int e = tid + r * 256;                    // 16384
        lds[e >> 10][e & 1023] = src[e];
    }
    __syncthreads();
#pragma unroll
    for (int half = 0; half < 2; ++half) {
        int k = tid + half * 256;
        int n = g_idx[b * KK + k] & 1023;
        float scl = fminf(fmaxf(g_scal[b * KK + k], 0.f), 1.f);
        float* dst = g_xg + ((size_t)(b * 512 + k) * 8 + t) * 128 + c0;
#pragma unroll
        for (int cc = 0; cc < 16; ++cc)
            dst[cc] = lds[cc][n] * scl;
    }
}

// ---------------- K_wt: one-time weight transposes for the GEMMs ----------------
__global__ void k_wt(const float* __restrict__ w_in, const float* __restrict__ w_out) {
    int e = blockIdx.x * 256 + threadIdx.x;       // grid covers 65536
    if (e < 65536) { int j = e >> 7; int c = e & 127; g_wint[c * 512 + j] = w_in[e]; }
    if (e < 32768) { int i = e >> 8; int c = e & 255; g_woutt[c * 128 + i] = w_out[e]; }
}

// ---------------- K_rms: rmsnorm rows of g_xg -> g_zn ----------------
__global__ __launch_bounds__(256) void k_rms(const float* __restrict__ w) {
    int r = blockIdx.x * 4 + (threadIdx.x >> 6);  // one wave per row
    int l = threadIdx.x & 63;
    const float* src = g_xg + (size_t)r * 128;
    float2 v = *(const float2*)(src + l * 2);
    float ss = v.x * v.x + v.y * v.y;
#pragma unroll
    for (int off = 32; off; off >>= 1) ss += __shfl_down(ss, off, 64);
    ss = __shfl(ss, 0, 64);
    float rstd = rsqrtf(ss * (1.f / 128.f) + 1e-5f);
    float* dst = g_zn + (size_t)r * 128;
    dst[l * 2]     = v.x * rstd * w[l * 2];
    dst[l * 2 + 1] = v.y * rstd * w[l * 2 + 1];
}

// ---------------- K_gemm: fp32 tiled GEMM, tile 128x128, K-chunks of 32 ----------------
template<int KTOT, int NTOT, int MODE>
__global__ __launch_bounds__(256, 2) void k_gemm() {
    __shared__ float At[32][132];
    __shared__ float Bs[32][128];
    const float* A  = (MODE == 0) ? g_zn : g_y;
    const float* Bt = (MODE == 0) ? g_wint : g_woutt;
    float* Cc       = (MODE == 0) ? g_xz : g_zs;
    const int NT = NTOT / 128;
    int mt = blockIdx.x / NT;
    int nt = blockIdx.x % NT;
    int tid = threadIdx.x;
    int mi = tid & 15;
    int ni = tid >> 4;

    float4 acc[2][2][4];
#pragma unroll
    for (int a = 0; a < 2; ++a)
#pragma unroll
        for (int bq = 0; bq < 2; ++bq)
#pragma unroll
            for (int rr = 0; rr < 4; ++rr)
                acc[a][bq][rr] = make_float4(0.f, 0.f, 0.f, 0.f);

    for (int kc = 0; kc < KTOT; kc += 32) {
#pragma unroll
        for (int i = 0; i < 16; ++i) {
            int e = tid + i * 256;
            int m = e >> 5, c = e & 31;
            At[c][m] = A[(size_t)(mt * 128 + m) * KTOT + kc + c];
        }
#pragma unroll
        for (int i = 0; i < 16; ++i) {
            int e = tid + i * 256;
            int c = e >> 7, n = e & 127;
            Bs[c][n] = Bt[(size_t)(kc + c) * NTOT + nt * 128 + n];
        }
        __syncthreads();
#pragma unroll 8
        for (int c = 0; c < 32; ++c) {
            float4 a0 = *(const float4*)&At[c][4 * mi];
            float4 a1 = *(const float4*)&At[c][64 + 4 * mi];
            float4 b0 = *(const float4*)&Bs[c][4 * ni];
            float4 b1 = *(const float4*)&Bs[c][64 + 4 * ni];
            float ar[8] = {a0.x, a0.y, a0.z, a0.w, a1.x, a1.y, a1.z, a1.w};
#pragma unroll
            for (int r = 0; r < 8; ++r) {
                int a = r >> 2, rr = r & 3;
                acc[a][0][rr].x += ar[r] * b0.x; acc[a][0][rr].y += ar[r] * b0.y;
                acc[a][0][rr].z += ar[r] * b0.z; acc[a][0][rr].w += ar[r] * b0.w;
                acc[a][1][rr].x += ar[r] * b1.x; acc[a][1][rr].y += ar[r] * b1.y;
                acc[a][1][rr].z += ar[r] * b1.z; acc[a][1][rr].w += ar[r] * b1.w;
            }
        }
        __syncthreads();
    }

#pragma unroll
    for (int a = 0; a < 2; ++a)
#pragma unroll
        for (int rr = 0; rr < 4; ++rr) {
            int r = mt * 128 + a * 64 + 4 * mi + rr;
#pragma unroll
            for (int bq = 0; bq < 2; ++bq) {
                int col = nt * 128 + bq * 64 + 4 * ni;
                if (MODE == 0) {
                    *(float4*)&Cc[(size_t)r * NTOT + col] = acc[a][bq][rr];
                } else {
                    int bb = r >> 12;             // r = (bb*512 + k)*8 + t
                    int k = (r >> 3) & 511;
                    int t = r & 7;
                    *(float4*)&Cc[((size_t)(bb * 8 + t) * 512 + k) * 128 + col] = acc[a][bq][rr];
                }
            }
        }
}

// ---------------- K_scan: conv + x_proj + dt_proj + selective scan + gate ----------------
__global__ __launch_bounds__(256, 2) void k_scan(const float* __restrict__ w_xp,
                        const float* __restrict__ conv_w, const float* __restrict__ conv_b,
                        const float* __restrict__ w_dt, const float* __restrict__ b_dt,
                        const float* __restrict__ A_log, const float* __restrict__ Dp) {
    __shared__ float xcv[8][256];
    __shared__ float xdbl[8][40];
    int tok = blockIdx.x;                         // b*512 + k
    int tid = threadIdx.x;
    const float* xzr = g_xz + (size_t)tok * 8 * 512;

    {   // causal depthwise conv (k=4, left pad 3) + bias + silu
        int d = tid;
        float w0 = conv_w[d * 4 + 0], w1 = conv_w[d * 4 + 1];
        float w2 = conv_w[d * 4 + 2], w3 = conv_w[d * 4 + 3];
        float cb = conv_b[d];
        float x0 = 0.f, x1 = 0.f, x2 = 0.f;
#pragma unroll
        for (int t = 0; t < 8; ++t) {
            float x3 = xzr[t * 512 + d];
            float v = x0 * w0 + x1 * w1 + x2 * w2 + x3 * w3 + cb;
            v = v / (1.f + expf(-v));
            xcv[t][d] = v;
            x0 = x1; x1 = x2; x2 = x3;
        }
    }
    __syncthreads();

#pragma unroll
    for (int r = 0; r < 2; ++r) {                 // x_proj (8,256)@(40,256)^T
        int e = tid + r * 256;
        if (e < 320) {
            int t = e / 40, j = e % 40;
            const float4* wr = (const float4*)(w_xp + j * 256);
            const float4* xr = (const float4*)xcv[t];
            float acc = 0.f;
#pragma unroll 8
            for (int c = 0; c < 64; ++c) {
                float4 w4 = wr[c], x4 = xr[c];
                acc += x4.x * w4.x + x4.y * w4.y + x4.z * w4.z + x4.w * w4.w;
            }
            xdbl[t][j] = acc;
        }
    }
    __syncthreads();

    {   // dt_proj + softplus + selective scan, 16 states in registers
        int d = tid;
        float wdt[8];
#pragma unroll
        for (int r = 0; r < 8; ++r) wdt[r] = w_dt[d * 8 + r];
        float bdt = b_dt[d];
        float Av[16], h[16];
#pragma unroll
        for (int s = 0; s < 16; ++s) { Av[s] = -expf(A_log[d * 16 + s]); h[s] = 0.f; }
        float Dd = Dp[d];
        float* yr = g_y + (size_t)tok * 8 * 256;
#pragma unroll
        for (int t = 0; t < 8; ++t) {
            float dtv = bdt;
#pragma unroll
            for (int r = 0; r < 8; ++r) dtv += xdbl[t][r] * wdt[r];
            dtv = dtv > 20.f ? dtv : logf(1.f + expf(dtv));
            float u = xcv[t][d];
            float db = dtv * u;
            float y = 0.f;
#pragma unroll
            for (int s = 0; s < 16; ++s) {
                h[s] = h[s] * expf(dtv * Av[s]) + db * xdbl[t][8 + s];
                y += h[s] * xdbl[t][24 + s];
            }
            y += u * Dd;
            float zg = xzr[t * 512 + 256 + d];
            y *= zg / (1.f + expf(-zg));
            yr[t * 256 + d] = y;
        }
    }
}

// ---------------- K6: qkv projection, 32 tokens per block ----------------
__global__ __launch_bounds__(256) void k_qkv(const float* __restrict__ wi,
                                             const float* __restrict__ bi) {
    __shared__ float zr[32][128];                 // 16 KB
    int tok0 = blockIdx.x * 32;                   // 1024 blocks
    int tid = threadIdx.x;
#pragma unroll
    for (int r = 0; r < 16; ++r) {
        int e = tid + r * 256;
        zr[e >> 7][e & 127] = g_zs[(size_t)tok0 * 128 + e];
    }
    __syncthreads();
#pragma unroll
    for (int pass = 0; pass < 2; ++pass) {
        int j = tid + pass * 256;
        if (j < 384) {
            const float* wr = wi + j * 128;
            float bv = bi[j];
            float acc[32];
#pragma unroll
            for (int t = 0; t < 32; ++t) acc[t] = bv;
            for (int c = 0; c < 128; ++c) {
                float wv = wr[c];
#pragma unroll
                for (int t = 0; t < 32; ++t) acc[t] += zr[t][c] * wv;
            }
#pragma unroll
            for (int t = 0; t < 32; ++t)
                g_qkv[(size_t)(tok0 + t) * 384 + j] = acc[t];
        }
    }
}

// ---------------- K7: MFMA attention per (bt, head, 32-q-tile) ----------------
// Dynamic LDS layout (bytes):
//   Kl:  [512][40] bf16  @0        (40960)   -- K rows, pad 40 keeps b128 reads ~conflict-free
//   Vt:  [32][520] bf16  @40960    (33280)   -- V transposed
//   Pl:  [32][520] bf16  @74240    (33280)   -- probabilities (S-layout -> A-frag transpose)
//   Op:  [4][32][33] f32 overlays Kl (dead after phase 1)
#define ATTN_LDS 107520
__global__ __launch_bounds__(256, 1) void k_attn3() {
    extern __shared__ char smem[];
    ushort* Kl = (ushort*)smem;
    ushort* Vt = (ushort*)(smem + 40960);
    ushort* Pl = (ushort*)(smem + 74240);
    __shared__ float statsM[4][32];
    __shared__ float statsS[4][32];

    int blk = blockIdx.x;                         // 1024 = 64 bt * 4 h * 4 qt
    int qt = blk & 3, h = (blk >> 2) & 3, bt = blk >> 4;
    int q0 = qt * 32;
    int tid = threadIdx.x;
    int w = tid >> 6, lane = tid & 63;
    int c = lane & 15, g = lane >> 4;
    const float* QKV = g_qkv + (size_t)bt * 512 * 384;
    const float rs = 0.17677669529663687f;        // 1/sqrt(32)

    // Q fragments direct from global (A-frag: row = c, k(d) = g*8+j)
    short8 qf[2];
#pragma unroll
    for (int i = 0; i < 2; ++i) {
        const float* qp = QKV + (size_t)(q0 + i * 16 + c) * 384 + h * 32 + g * 8;
        float4 a = *(const float4*)qp;
        float4 b = *(const float4*)(qp + 4);
        U8 t;
        t.u[0] = f2bu(a.x * rs); t.u[1] = f2bu(a.y * rs);
        t.u[2] = f2bu(a.z * rs); t.u[3] = f2bu(a.w * rs);
        t.u[4] = f2bu(b.x * rs); t.u[5] = f2bu(b.y * rs);
        t.u[6] = f2bu(b.z * rs); t.u[7] = f2bu(b.w * rs);
        qf[i] = t.v;
    }

    // stage K -> Kl[tok][d], V -> Vt[d][tok]  (bf16)
#pragma unroll
    for (int r = 0; r < 8; ++r) {
        int tok = r * 64 + (tid >> 2);
        int dblk = (tid & 3) * 8;
        const float* kp = QKV + (size_t)tok * 384 + 128 + h * 32 + dblk;
        float4 ka = *(const float4*)kp,       kb4 = *(const float4*)(kp + 4);
        float4 va = *(const float4*)(kp+128), vb4 = *(const float4*)(kp + 132);
        U8 t;
        t.u[0] = f2bu(ka.x); t.u[1] = f2bu(ka.y); t.u[2] = f2bu(ka.z); t.u[3] = f2bu(ka.w);
        t.u[4] = f2bu(kb4.x); t.u[5] = f2bu(kb4.y); t.u[6] = f2bu(kb4.z); t.u[7] = f2bu(kb4.w);
        *(short8*)&Kl[tok * 40 + dblk] = t.v;
        Vt[(dblk + 0) * 520 + tok] = f2bu(va.x);
        Vt[(dblk + 1) * 520 + tok] = f2bu(va.y);
        Vt[(dblk + 2) * 520 + tok] = f2bu(va.z);
        Vt[(dblk + 3) * 520 + tok] = f2bu(va.w);
        Vt[(dblk + 4) * 520 + tok] = f2bu(vb4.x);
        Vt[(dblk + 5) * 520 + tok] = f2bu(vb4.y);
        Vt[(dblk + 6) * 520 + tok] = f2bu(vb4.z);
        Vt[(dblk + 7) * 520 + tok] = f2bu(vb4.w);
    }
    __syncthreads();

    // ---- phase 1: S(32 x 128-slice) in regs; wave w owns kcols [w*128, w*128+128) ----
    int kbase = w * 128;
    f32x4 S[2][8];
    f32x4 zero = {0.f, 0.f, 0.f, 0.f};
#pragma unroll
    for (int ks = 0; ks < 8; ++ks) {
        // B-frag: col = c -> kcol, k(d) = g*8+j : K^T[d][kcol] = Kl[kcol][d]
        short8 kf = *(const short8*)&Kl[(kbase + ks * 16 + c) * 40 + g * 8];
        S[0][ks] = __builtin_amdgcn_mfma_f32_16x16x32_bf16(qf[0], kf, zero, 0, 0, 0);
        S[1][ks] = __builtin_amdgcn_mfma_f32_16x16x32_bf16(qf[1], kf, zero, 0, 0, 0);
    }

    // ---- row max (C/D: col=c, row = i*16 + g*4 + r) ----
    float pmax[2][4];
#pragma unroll
    for (int i = 0; i < 2; ++i)
#pragma unroll
        for (int r = 0; r < 4; ++r) {
            float m = S[i][0][r];
#pragma unroll
            for (int ks = 1; ks < 8; ++ks) m = fmaxf(m, S[i][ks][r]);
            pmax[i][r] = m;
        }
#pragma unroll
    for (int msk = 1; msk <= 8; msk <<= 1)
#pragma unroll
        for (int i = 0; i < 2; ++i)
#pragma unroll
            for (int r = 0; r < 4; ++r)
                pmax[i][r] = fmaxf(pmax[i][r], __shfl_xor(pmax[i][r], msk, 64));
    if (c == 0) {
#pragma unroll
        for (int i = 0; i < 2; ++i)
#pragma unroll
            for (int r = 0; r < 4; ++r)
                statsM[w][i * 16 + g * 4 + r] = pmax[i][r];
    }
    __syncthreads();

    // ---- P = exp(S - m) -> bf16 LDS; partial row sums ----
    float psum[2][4];
#pragma unroll
    for (int i = 0; i < 2; ++i)
#pragma unroll
        for (int r = 0; r < 4; ++r) {
            int q = i * 16 + g * 4 + r;
            float m = fmaxf(fmaxf(statsM[0][q], statsM[1][q]),
                            fmaxf(statsM[2][q], statsM[3][q]));
            float ps = 0.f;
#pragma unroll
            for (int ks = 0; ks < 8; ++ks) {
                float p = __expf(S[i][ks][r] - m);
                ps += p;
                Pl[q * 520 + kbase + ks * 16 + c] = f2bu(p);
            }
            psum[i][r] = ps;
        }
#pragma unroll
    for (int msk = 1; msk <= 8; msk <<= 1)
#pragma unroll
        for (int i = 0; i < 2; ++i)
#pragma unroll
            for (int r = 0; r < 4; ++r)
                psum[i][r] += __shfl_xor(psum[i][r], msk, 64);
    if (c == 0) {
#pragma unroll
        for (int i = 0; i < 2; ++i)
#pragma unroll
            for (int r = 0; r < 4; ++r)
                statsS[w][i * 16 + g * 4 + r] = psum[i][r];
    }
    __syncthreads();

    // ---- phase 3: O_partial = P_slice @ V_slice ----
    f32x4 o[2][2];
    o[0][0] = zero; o[0][1] = zero; o[1][0] = zero; o[1][1] = zero;
#pragma unroll
    for (int kst = 0; kst < 4; ++kst) {
        int k0 = kbase + kst * 32;
        short8 pa0 = *(const short8*)&Pl[(c) * 520 + k0 + g * 8];
        short8 pa1 = *(const short8*)&Pl[(16 + c) * 520 + k0 + g * 8];
        short8 vb0 = *(const short8*)&Vt[(c) * 520 + k0 + g * 8];
        short8 vb1 = *(const short8*)&Vt[(16 + c) * 520 + k0 + g * 8];
        o[0][0] = __builtin_amdgcn_mfma_f32_16x16x32_bf16(pa0, vb0, o[0][0], 0, 0, 0);
        o[0][1] = __builtin_amdgcn_mfma_f32_16x16x32_bf16(pa0, vb1, o[0][1], 0, 0, 0);
        o[1][0] = __builtin_amdgcn_mfma_f32_16x16x32_bf16(pa1, vb0, o[1][0], 0, 0, 0);
        o[1][1] = __builtin_amdgcn_mfma_f32_16x16x32_bf16(pa1, vb1, o[1][1], 0, 0, 0);
    }

    // ---- cross-wave reduce (partials overlay dead Kl region) ----
    float* Op = (float*)smem;                     // [4][32][33]
#pragma unroll
    for (int i = 0; i < 2; ++i)
#pragma unroll
        for (int jd = 0; jd < 2; ++jd)
#pragma unroll
            for (int r = 0; r < 4; ++r)
                Op[(w * 32 + i * 16 + g * 4 + r) * 33 + jd * 16 + c] = o[i][jd][r];
    __syncthreads();

    int q = tid >> 3;
    int d0 = (tid & 7) * 4;
    float lrow = statsS[0][q] + statsS[1][q] + statsS[2][q] + statsS[3][q];
    float inv = 1.f / lrow;
    float* orow = g_o + ((size_t)(bt * 512) + q0 + q) * 128 + h * 32 + d0;
#pragma unroll
    for (int dd = 0; dd < 4; ++dd) {
        float s = Op[(0 * 32 + q) * 33 + d0 + dd] + Op[(1 * 32 + q) * 33 + d0 + dd]
                + Op[(2 * 32 + q) * 33 + d0 + dd] + Op[(3 * 32 + q) * 33 + d0 + dd];
        orow[dd] = s * inv;
    }
}

// ------- K8: out_proj + residual + LayerNorm + scatter (fp32 d_out) -------
__global__ __launch_bounds__(128) void k_final(const float* __restrict__ x_in,
                       float* __restrict__ out,
                       const float* __restrict__ wo, const float* __restrict__ bo,
                       const float* __restrict__ ln_w, const float* __restrict__ ln_b) {
    __shared__ float orow[128];
    __shared__ float sh[4];
    int tk = blockIdx.x;                          // bt*512 + k
    int bt = tk >> 9, k = tk & 511;
    int b = bt >> 3;
    int i = threadIdx.x;                          // 128 threads
    orow[i] = g_o[(size_t)tk * 128 + i];
    __syncthreads();
    const float* wr = wo + i * 128;
    float acc = bo[i];
    for (int j = 0; j < 128; ++j) acc += orow[j] * wr[j];
    float xi = g_zs[(size_t)tk * 128 + i] + acc;
    float s1 = xi, s2 = xi * xi;
#pragma unroll
    for (int off = 32; off; off >>= 1) {
        s1 += __shfl_down(s1, off, 64);
        s2 += __shfl_down(s2, off, 64);
    }
    if ((i & 63) == 0) { sh[(i >> 6) * 2] = s1; sh[(i >> 6) * 2 + 1] = s2; }
    __syncthreads();
    float mu = (sh[0] + sh[2]) * (1.f / 128.f);
    float var = (sh[1] + sh[3]) * (1.f / 128.f) - mu * mu;
    float yo = (xi - mu) * rsqrtf(fmaxf(var, 0.f) + 1e-5f) * ln_w[i] + ln_b[i];
    int n = g_idx[b * KK + k] & 1023;
    size_t oi = (((size_t)(bt * 128 + i)) << 10) + n;
    out[oi] = x_in[oi] + yo;
}

extern "C" void kernel_launch(void* const* d_in, const int* in_sizes, int n_in,
                              void* d_out, int out_size, void* d_ws, size_t ws_size,
                              hipStream_t stream) {
    const float* x_in      = (const float*)d_in[0];
    const float* norm1_w   = (const float*)d_in[1];
    const float* in_proj_w = (const float*)d_in[2];
    const float* conv1d_w  = (const float*)d_in[3];
    const float* conv1d_b  = (const float*)d_in[4];
    const float* x_proj_w  = (const float*)d_in[5];
    const float* dt_proj_w = (const float*)d_in[6];
    const float* dt_proj_b = (const float*)d_in[7];
    const float* A_log     = (const float*)d_in[8];
    const float* Dp        = (const float*)d_in[9];
    const float* out_proj_w= (const float*)d_in[10];
    const float* r1_w      = (const float*)d_in[11];
    const float* r1_b      = (const float*)d_in[12];
    const float* r2_w      = (const float*)d_in[13];
    const float* r2_b      = (const float*)d_in[14];
    const float* attn_in_w = (const float*)d_in[15];
    const float* attn_in_b = (const float*)d_in[16];
    const float* attn_out_w= (const float*)d_in[17];
    const float* attn_out_b= (const float*)d_in[18];
    const float* ln_w      = (const float*)d_in[19];
    const float* ln_b      = (const float*)d_in[20];
    // d_in[21]: current_epoch == 20 (static) -> ratio 0.5 -> K = 512

    float* out = (float*)d_out;

    static bool attr_set = false;
    if (!attr_set) {
        hipFuncSetAttribute(reinterpret_cast<const void*>(k_attn3),
                            hipFuncAttributeMaxDynamicSharedMemorySize, ATTN_LDS);
        attr_set = true;
    }

    t_init<<<16, 256, 0, stream>>>(0);
    k_mean<<<4096, 256, 0, stream>>>(x_in);
    k_router_conv<<<1024, 256, 0, stream>>>(r1_w, r1_b);
    k_topk<<<8, 1024, 0, stream>>>(r2_w, r2_b);
    k_copy<<<8192, 256, 0, stream>>>((const float4*)x_in, (float4*)d_out);
    k_gather<<<512, 256, 0, stream>>>(x_in);
    k_wt<<<256, 256, 0, stream>>>(in_proj_w, out_proj_w);
    k_rms<<<8192, 256, 0, stream>>>(norm1_w);
    k_gemm<128, 512, 0><<<1024, 256, 0, stream>>>();   // in_proj
    k_scan<<<4096, 256, 0, stream>>>(x_proj_w, conv1d_w, conv1d_b,
                                     dt_proj_w, dt_proj_b, A_log, Dp);
    k_gemm<256, 128, 1><<<256, 256, 0, stream>>>();    // out_proj (+ layout scatter)
    k_qkv<<<1024, 256, 0, stream>>>(attn_in_w, attn_in_b);
    k_attn3<<<1024, 256, ATTN_LDS, stream>>>();
    k_final<<<32768, 128, 0, stream>>>(x_in, out, attn_out_w, attn_out_b, ln_w, ln_b);
}

// Round 3
// 915.295 us; speedup vs baseline: 2.8031x; 1.2605x over previous
//
#include <hip/hip_runtime.h>
#include <hip/hip_bf16.h>

typedef __hip_bfloat16 bf16;
typedef __attribute__((ext_vector_type(8))) short short8;
typedef __attribute__((ext_vector_type(4))) float f32x4;

#define KK 512    // kept tokens (epoch=20 -> ratio 0.5, K = 1024/2)

// ---- static device scratch (outside all harness buffers) ----
__device__ float g_xm[1048576];        // (B,C,H,W) router mean
__device__ float g_h1[262144];         // (B,32,H,W) router hidden
__device__ float g_scal[4096];         // (B,K) STE scale
__device__ int   g_idx[4096];          // (B,K) selected spatial indices (sorted)
__device__ float g_xg[4194304];        // (B,K,T,C) gathered+scaled tokens (dense)
__device__ float g_zs[4194304];        // (B*T, K, C) mamba output
__device__ float g_qkv[12582912];      // (B*T, K, 384) attn qkv
__device__ float g_o[4194304];         // (B*T, K, C) attn context
// mamba pipeline scratch
__device__ float g_zn[4194304];        // (B*K*T, 128) rmsnormed tokens
__device__ float g_xz[16777216];       // (B*K*T, 512) in_proj output
__device__ float g_y[8388608];         // (B*K*T, 256) gated scan output
__device__ float g_wint[65536];        // in_proj_w transposed (128 x 512)
__device__ float g_woutt[32768];       // out_proj_w transposed (256 x 128)
__device__ float g_wot[16384];         // attn_out_w transposed (128 x 128)
__device__ float g_zo[4194304];        // (bt*128+c, kpos) final LN'd tokens, transposed

__device__ __forceinline__ float b2f(bf16 v) { return __bfloat162float(v); }

// round-to-nearest-even f32 -> bf16 bits
__device__ __forceinline__ ushort f2bu(float f) {
    union { float f; unsigned u; } v; v.f = f;
    unsigned r = v.u + 0x7fffu + ((v.u >> 16) & 1u);
    return (ushort)(r >> 16);
}

union U8 { short8 v; ushort u[8]; };

// ---------------- P1: init tables with valid defaults (defensive) ----------------
__global__ void t_init(int dummy) {
    int e = blockIdx.x * 256 + threadIdx.x;
    if (e < 4096) { g_scal[e] = 1.0f; g_idx[e] = e & 511; }
}

// ---------------- K1: xm = mean over T of x_in ----------------
__global__ void k_mean(const float* __restrict__ x) {
    int id = blockIdx.x * 256 + threadIdx.x;      // < 8*128*1024
    int n = id & 1023;
    int c = (id >> 10) & 127;
    int b = id >> 17;
    float s = 0.f;
#pragma unroll
    for (int t = 0; t < 8; ++t)
        s += x[(((b * 8 + t) * 128 + c) << 10) + n];
    g_xm[id] = s * 0.125f;
}

// ---------------- K2: 3x3 conv 128->32 + bias + LeakyReLU ----------------
__global__ void k_router_conv(const float* __restrict__ w, const float* __restrict__ bias) {
    int id = blockIdx.x * 256 + threadIdx.x;      // < 8*32*1024
    int x = id & 31;
    int y = (id >> 5) & 31;
    int oc = (id >> 10) & 31;
    int b = id >> 15;
    const float* xb = g_xm + b * 131072;
    float acc = bias[oc];
    for (int ic = 0; ic < 128; ++ic) {
        const float* wr = w + (oc * 128 + ic) * 9;
        const float* xr = xb + ic * 1024;
#pragma unroll
        for (int ky = 0; ky < 3; ++ky) {
            int yy = y + ky - 1;
            if (yy < 0 || yy > 31) continue;
#pragma unroll
            for (int kx = 0; kx < 3; ++kx) {
                int xx = x + kx - 1;
                if (xx < 0 || xx > 31) continue;
                acc += xr[yy * 32 + xx] * wr[ky * 3 + kx];
            }
        }
    }
    g_h1[id] = acc >= 0.f ? acc : 0.01f * acc;
}

// -------- K3: 1x1 conv + sigmoid + exact top-k(512) into g_idx/g_scal --------
__global__ __launch_bounds__(1024) void k_topk(const float* __restrict__ r2w,
                                               const float* __restrict__ r2b) {
    __shared__ float sc[1024];
    __shared__ int flg[1024];
    int b = blockIdx.x;
    int n = threadIdx.x;
    float a = r2b[0];
#pragma unroll
    for (int ic = 0; ic < 32; ++ic)
        a += g_h1[b * 32768 + ic * 1024 + n] * r2w[ic];
    float s = 1.f / (1.f + expf(-a));
    sc[n] = s;
    __syncthreads();
    // jax top_k tie-breaking (lower index wins) -> rank is a permutation of 0..1023
    int rank = 0;
    for (int j = 0; j < 1024; ++j) {
        float v = sc[j];
        rank += (v > s) || (v == s && j < n);
    }
    int sel = rank < KK ? 1 : 0;
    flg[n] = sel;
    __syncthreads();
    for (int d = 1; d < 1024; d <<= 1) {          // inclusive Hillis-Steele scan
        int add = (n >= d) ? flg[n - d] : 0;
        __syncthreads();
        flg[n] += add;
        __syncthreads();
    }
    if (sel) {
        int pos = (flg[n] - 1) & 511;
        g_idx[b * KK + pos] = n;
        g_scal[b * KK + pos] = s / (s + 1e-6f);
    }
}

// ------ K4b: coalesced gather: g_xg[(b,k),(t,c)] = x_in[b,t,c,n(k)] * scl(k) ------
__global__ __launch_bounds__(256) void k_gather(const float* __restrict__ x) {
    __shared__ float lds[16][1024];               // 64 KB
    int blk = blockIdx.x;                         // 512 = 8b * 8t * 8cc
    int cchunk = blk & 7;
    int t = (blk >> 3) & 7;
    int b = blk >> 6;
    int c0 = cchunk * 16;
    int tid = threadIdx.x;
    const float* src = x + ((size_t)(b * 8 + t) * 128 + c0) * 1024;
#pragma unroll
    for (int r = 0; r < 64; ++r) {
        int e = tid + r * 256;                    // 16384
        lds[e >> 10][e & 1023] = src[e];
    }
    __syncthreads();
#pragma unroll
    for (int half = 0; half < 2; ++half) {
        int k = tid + half * 256;
        int n = g_idx[b * KK + k] & 1023;
        float scl = fminf(fmaxf(g_scal[b * KK + k], 0.f), 1.f);
        float* dst = g_xg + ((size_t)(b * 512 + k) * 8 + t) * 128 + c0;
#pragma unroll
        for (int cc = 0; cc < 16; ++cc)
            dst[cc] = lds[cc][n] * scl;
    }
}

// ---------------- K_wt: one-time weight transposes for the GEMMs ----------------
__global__ void k_wt(const float* __restrict__ w_in, const float* __restrict__ w_out,
                     const float* __restrict__ w_ao) {
    int e = blockIdx.x * 256 + threadIdx.x;       // grid covers 65536
    if (e < 65536) { int j = e >> 7; int c = e & 127; g_wint[c * 512 + j] = w_in[e]; }
    if (e < 32768) { int i = e >> 8; int c = e & 255; g_woutt[c * 128 + i] = w_out[e]; }
    if (e < 16384) { int i = e >> 7; int c = e & 127; g_wot[c * 128 + i] = w_ao[e]; }
}

// ---------------- K_rms: rmsnorm rows of g_xg -> g_zn ----------------
__global__ __launch_bounds__(256) void k_rms(const float* __restrict__ w) {
    int r = blockIdx.x * 4 + (threadIdx.x >> 6);  // one wave per row
    int l = threadIdx.x & 63;
    const float* src = g_xg + (size_t)r * 128;
    float2 v = *(const float2*)(src + l * 2);
    float ss = v.x * v.x + v.y * v.y;
#pragma unroll
    for (int off = 32; off; off >>= 1) ss += __shfl_down(ss, off, 64);
    ss = __shfl(ss, 0, 64);
    float rstd = rsqrtf(ss * (1.f / 128.f) + 1e-5f);
    float* dst = g_zn + (size_t)r * 128;
    dst[l * 2]     = v.x * rstd * w[l * 2];
    dst[l * 2 + 1] = v.y * rstd * w[l * 2 + 1];
}

// ---------------- K_gemm: fp32 tiled GEMM, tile 128x128, K-chunks of 32 ----------------
template<int KTOT, int NTOT, int MODE>
__global__ __launch_bounds__(256, 2) void k_gemm() {
    __shared__ float At[32][132];
    __shared__ float Bs[32][128];
    const float* A  = (MODE == 0) ? g_zn : g_y;
    const float* Bt = (MODE == 0) ? g_wint : g_woutt;
    float* Cc       = (MODE == 0) ? g_xz : g_zs;
    const int NT = NTOT / 128;
    int mt = blockIdx.x / NT;
    int nt = blockIdx.x % NT;
    int tid = threadIdx.x;
    int mi = tid & 15;
    int ni = tid >> 4;

    float4 acc[2][2][4];
#pragma unroll
    for (int a = 0; a < 2; ++a)
#pragma unroll
        for (int bq = 0; bq < 2; ++bq)
#pragma unroll
            for (int rr = 0; rr < 4; ++rr)
                acc[a][bq][rr] = make_float4(0.f, 0.f, 0.f, 0.f);

    for (int kc = 0; kc < KTOT; kc += 32) {
#pragma unroll
        for (int i = 0; i < 16; ++i) {
            int e = tid + i * 256;
            int m = e >> 5, c = e & 31;
            At[c][m] = A[(size_t)(mt * 128 + m) * KTOT + kc + c];
        }
#pragma unroll
        for (int i = 0; i < 16; ++i) {
            int e = tid + i * 256;
            int c = e >> 7, n = e & 127;
            Bs[c][n] = Bt[(size_t)(kc + c) * NTOT + nt * 128 + n];
        }
        __syncthreads();
#pragma unroll 8
        for (int c = 0; c < 32; ++c) {
            float4 a0 = *(const float4*)&At[c][4 * mi];
            float4 a1 = *(const float4*)&At[c][64 + 4 * mi];
            float4 b0 = *(const float4*)&Bs[c][4 * ni];
            float4 b1 = *(const float4*)&Bs[c][64 + 4 * ni];
            float ar[8] = {a0.x, a0.y, a0.z, a0.w, a1.x, a1.y, a1.z, a1.w};
#pragma unroll
            for (int r = 0; r < 8; ++r) {
                int a = r >> 2, rr = r & 3;
                acc[a][0][rr].x += ar[r] * b0.x; acc[a][0][rr].y += ar[r] * b0.y;
                acc[a][0][rr].z += ar[r] * b0.z; acc[a][0][rr].w += ar[r] * b0.w;
                acc[a][1][rr].x += ar[r] * b1.x; acc[a][1][rr].y += ar[r] * b1.y;
                acc[a][1][rr].z += ar[r] * b1.z; acc[a][1][rr].w += ar[r] * b1.w;
            }
        }
        __syncthreads();
    }

#pragma unroll
    for (int a = 0; a < 2; ++a)
#pragma unroll
        for (int rr = 0; rr < 4; ++rr) {
            int r = mt * 128 + a * 64 + 4 * mi + rr;
#pragma unroll
            for (int bq = 0; bq < 2; ++bq) {
                int col = nt * 128 + bq * 64 + 4 * ni;
                if (MODE == 0) {
                    *(float4*)&Cc[(size_t)r * NTOT + col] = acc[a][bq][rr];
                } else {
                    int bb = r >> 12;             // r = (bb*512 + k)*8 + t
                    int k = (r >> 3) & 511;
                    int t = r & 7;
                    *(float4*)&Cc[((size_t)(bb * 8 + t) * 512 + k) * 128 + col] = acc[a][bq][rr];
                }
            }
        }
}

// ---------------- K_scan: conv + x_proj + dt_proj + selective scan + gate ----------------
__global__ __launch_bounds__(256, 2) void k_scan(const float* __restrict__ w_xp,
                        const float* __restrict__ conv_w, const float* __restrict__ conv_b,
                        const float* __restrict__ w_dt, const float* __restrict__ b_dt,
                        const float* __restrict__ A_log, const float* __restrict__ Dp) {
    __shared__ float xcv[8][256];
    __shared__ float xdbl[8][40];
    int tok = blockIdx.x;                         // b*512 + k
    int tid = threadIdx.x;
    const float* xzr = g_xz + (size_t)tok * 8 * 512;

    {   // causal depthwise conv (k=4, left pad 3) + bias + silu
        int d = tid;
        float w0 = conv_w[d * 4 + 0], w1 = conv_w[d * 4 + 1];
        float w2 = conv_w[d * 4 + 2], w3 = conv_w[d * 4 + 3];
        float cb = conv_b[d];
        float x0 = 0.f, x1 = 0.f, x2 = 0.f;
#pragma unroll
        for (int t = 0; t < 8; ++t) {
            float x3 = xzr[t * 512 + d];
            float v = x0 * w0 + x1 * w1 + x2 * w2 + x3 * w3 + cb;
            v = v / (1.f + expf(-v));
            xcv[t][d] = v;
            x0 = x1; x1 = x2; x2 = x3;
        }
    }
    __syncthreads();

#pragma unroll
    for (int r = 0; r < 2; ++r) {                 // x_proj (8,256)@(40,256)^T
        int e = tid + r * 256;
        if (e < 320) {
            int t = e / 40, j = e % 40;
            const float4* wr = (const float4*)(w_xp + j * 256);
            const float4* xr = (const float4*)xcv[t];
            float acc = 0.f;
#pragma unroll 8
            for (int c = 0; c < 64; ++c) {
                float4 w4 = wr[c], x4 = xr[c];
                acc += x4.x * w4.x + x4.y * w4.y + x4.z * w4.z + x4.w * w4.w;
            }
            xdbl[t][j] = acc;
        }
    }
    __syncthreads();

    {   // dt_proj + softplus + selective scan, 16 states in registers
        int d = tid;
        float wdt[8];
#pragma unroll
        for (int r = 0; r < 8; ++r) wdt[r] = w_dt[d * 8 + r];
        float bdt = b_dt[d];
        float Av[16], h[16];
#pragma unroll
        for (int s = 0; s < 16; ++s) { Av[s] = -expf(A_log[d * 16 + s]); h[s] = 0.f; }
        float Dd = Dp[d];
        float* yr = g_y + (size_t)tok * 8 * 256;
#pragma unroll
        for (int t = 0; t < 8; ++t) {
            float dtv = bdt;
#pragma unroll
            for (int r = 0; r < 8; ++r) dtv += xdbl[t][r] * wdt[r];
            dtv = dtv > 20.f ? dtv : logf(1.f + expf(dtv));
            float u = xcv[t][d];
            float db = dtv * u;
            float y = 0.f;
#pragma unroll
            for (int s = 0; s < 16; ++s) {
                h[s] = h[s] * expf(dtv * Av[s]) + db * xdbl[t][8 + s];
                y += h[s] * xdbl[t][24 + s];
            }
            y += u * Dd;
            float zg = xzr[t * 512 + 256 + d];
            y *= zg / (1.f + expf(-zg));
            yr[t * 256 + d] = y;
        }
    }
}

// ---------------- K6: qkv projection, 32 tokens per block ----------------
__global__ __launch_bounds__(256) void k_qkv(const float* __restrict__ wi,
                                             const float* __restrict__ bi) {
    __shared__ float zr[32][128];                 // 16 KB
    int tok0 = blockIdx.x * 32;                   // 1024 blocks
    int tid = threadIdx.x;
#pragma unroll
    for (int r = 0; r < 16; ++r) {
        int e = tid + r * 256;
        zr[e >> 7][e & 127] = g_zs[(size_t)tok0 * 128 + e];
    }
    __syncthreads();
#pragma unroll
    for (int pass = 0; pass < 2; ++pass) {
        int j = tid + pass * 256;
        if (j < 384) {
            const float* wr = wi + j * 128;
            float bv = bi[j];
            float acc[32];
#pragma unroll
            for (int t = 0; t < 32; ++t) acc[t] = bv;
            for (int c = 0; c < 128; ++c) {
                float wv = wr[c];
#pragma unroll
                for (int t = 0; t < 32; ++t) acc[t] += zr[t][c] * wv;
            }
#pragma unroll
            for (int t = 0; t < 32; ++t)
                g_qkv[(size_t)(tok0 + t) * 384 + j] = acc[t];
        }
    }
}

// ---------------- K7: MFMA attention per (bt, head, 32-q-tile) ----------------
#define ATTN_LDS 107520
__global__ __launch_bounds__(256, 1) void k_attn3() {
    extern __shared__ char smem[];
    ushort* Kl = (ushort*)smem;
    ushort* Vt = (ushort*)(smem + 40960);
    ushort* Pl = (ushort*)(smem + 74240);
    __shared__ float statsM[4][32];
    __shared__ float statsS[4][32];

    int blk = blockIdx.x;                         // 1024 = 64 bt * 4 h * 4 qt
    int qt = blk & 3, h = (blk >> 2) & 3, bt = blk >> 4;
    int q0 = qt * 32;
    int tid = threadIdx.x;
    int w = tid >> 6, lane = tid & 63;
    int c = lane & 15, g = lane >> 4;
    const float* QKV = g_qkv + (size_t)bt * 512 * 384;
    const float rs = 0.17677669529663687f;        // 1/sqrt(32)

    short8 qf[2];
#pragma unroll
    for (int i = 0; i < 2; ++i) {
        const float* qp = QKV + (size_t)(q0 + i * 16 + c) * 384 + h * 32 + g * 8;
        float4 a = *(const float4*)qp;
        float4 b = *(const float4*)(qp + 4);
        U8 t;
        t.u[0] = f2bu(a.x * rs); t.u[1] = f2bu(a.y * rs);
        t.u[2] = f2bu(a.z * rs); t.u[3] = f2bu(a.w * rs);
        t.u[4] = f2bu(b.x * rs); t.u[5] = f2bu(b.y * rs);
        t.u[6] = f2bu(b.z * rs); t.u[7] = f2bu(b.w * rs);
        qf[i] = t.v;
    }

#pragma unroll
    for (int r = 0; r < 8; ++r) {
        int tok = r * 64 + (tid >> 2);
        int dblk = (tid & 3) * 8;
        const float* kp = QKV + (size_t)tok * 384 + 128 + h * 32 + dblk;
        float4 ka = *(const float4*)kp,       kb4 = *(const float4*)(kp + 4);
        float4 va = *(const float4*)(kp+128), vb4 = *(const float4*)(kp + 132);
        U8 t;
        t.u[0] = f2bu(ka.x); t.u[1] = f2bu(ka.y); t.u[2] = f2bu(ka.z); t.u[3] = f2bu(ka.w);
        t.u[4] = f2bu(kb4.x); t.u[5] = f2bu(kb4.y); t.u[6] = f2bu(kb4.z); t.u[7] = f2bu(kb4.w);
        *(short8*)&Kl[tok * 40 + dblk] = t.v;
        Vt[(dblk + 0) * 520 + tok] = f2bu(va.x);
        Vt[(dblk + 1) * 520 + tok] = f2bu(va.y);
        Vt[(dblk + 2) * 520 + tok] = f2bu(va.z);
        Vt[(dblk + 3) * 520 + tok] = f2bu(va.w);
        Vt[(dblk + 4) * 520 + tok] = f2bu(vb4.x);
        Vt[(dblk + 5) * 520 + tok] = f2bu(vb4.y);
        Vt[(dblk + 6) * 520 + tok] = f2bu(vb4.z);
        Vt[(dblk + 7) * 520 + tok] = f2bu(vb4.w);
    }
    __syncthreads();

    int kbase = w * 128;
    f32x4 S[2][8];
    f32x4 zero = {0.f, 0.f, 0.f, 0.f};
#pragma unroll
    for (int ks = 0; ks < 8; ++ks) {
        short8 kf = *(const short8*)&Kl[(kbase + ks * 16 + c) * 40 + g * 8];
        S[0][ks] = __builtin_amdgcn_mfma_f32_16x16x32_bf16(qf[0], kf, zero, 0, 0, 0);
        S[1][ks] = __builtin_amdgcn_mfma_f32_16x16x32_bf16(qf[1], kf, zero, 0, 0, 0);
    }

    float pmax[2][4];
#pragma unroll
    for (int i = 0; i < 2; ++i)
#pragma unroll
        for (int r = 0; r < 4; ++r) {
            float m = S[i][0][r];
#pragma unroll
            for (int ks = 1; ks < 8; ++ks) m = fmaxf(m, S[i][ks][r]);
            pmax[i][r] = m;
        }
#pragma unroll
    for (int msk = 1; msk <= 8; msk <<= 1)
#pragma unroll
        for (int i = 0; i < 2; ++i)
#pragma unroll
            for (int r = 0; r < 4; ++r)
                pmax[i][r] = fmaxf(pmax[i][r], __shfl_xor(pmax[i][r], msk, 64));
    if (c == 0) {
#pragma unroll
        for (int i = 0; i < 2; ++i)
#pragma unroll
            for (int r = 0; r < 4; ++r)
                statsM[w][i * 16 + g * 4 + r] = pmax[i][r];
    }
    __syncthreads();

    float psum[2][4];
#pragma unroll
    for (int i = 0; i < 2; ++i)
#pragma unroll
        for (int r = 0; r < 4; ++r) {
            int q = i * 16 + g * 4 + r;
            float m = fmaxf(fmaxf(statsM[0][q], statsM[1][q]),
                            fmaxf(statsM[2][q], statsM[3][q]));
            float ps = 0.f;
#pragma unroll
            for (int ks = 0; ks < 8; ++ks) {
                float p = __expf(S[i][ks][r] - m);
                ps += p;
                Pl[q * 520 + kbase + ks * 16 + c] = f2bu(p);
            }
            psum[i][r] = ps;
        }
#pragma unroll
    for (int msk = 1; msk <= 8; msk <<= 1)
#pragma unroll
        for (int i = 0; i < 2; ++i)
#pragma unroll
            for (int r = 0; r < 4; ++r)
                psum[i][r] += __shfl_xor(psum[i][r], msk, 64);
    if (c == 0) {
#pragma unroll
        for (int i = 0; i < 2; ++i)
#pragma unroll
            for (int r = 0; r < 4; ++r)
                statsS[w][i * 16 + g * 4 + r] = psum[i][r];
    }
    __syncthreads();

    f32x4 o[2][2];
    o[0][0] = zero; o[0][1] = zero; o[1][0] = zero; o[1][1] = zero;
#pragma unroll
    for (int kst = 0; kst < 4; ++kst) {
        int k0 = kbase + kst * 32;
        short8 pa0 = *(const short8*)&Pl[(c) * 520 + k0 + g * 8];
        short8 pa1 = *(const short8*)&Pl[(16 + c) * 520 + k0 + g * 8];
        short8 vb0 = *(const short8*)&Vt[(c) * 520 + k0 + g * 8];
        short8 vb1 = *(const short8*)&Vt[(16 + c) * 520 + k0 + g * 8];
        o[0][0] = __builtin_amdgcn_mfma_f32_16x16x32_bf16(pa0, vb0, o[0][0], 0, 0, 0);
        o[0][1] = __builtin_amdgcn_mfma_f32_16x16x32_bf16(pa0, vb1, o[0][1], 0, 0, 0);
        o[1][0] = __builtin_amdgcn_mfma_f32_16x16x32_bf16(pa1, vb0, o[1][0], 0, 0, 0);
        o[1][1] = __builtin_amdgcn_mfma_f32_16x16x32_bf16(pa1, vb1, o[1][1], 0, 0, 0);
    }

    float* Op = (float*)smem;                     // [4][32][33]
#pragma unroll
    for (int i = 0; i < 2; ++i)
#pragma unroll
        for (int jd = 0; jd < 2; ++jd)
#pragma unroll
            for (int r = 0; r < 4; ++r)
                Op[(w * 32 + i * 16 + g * 4 + r) * 33 + jd * 16 + c] = o[i][jd][r];
    __syncthreads();

    int q = tid >> 3;
    int d0 = (tid & 7) * 4;
    float lrow = statsS[0][q] + statsS[1][q] + statsS[2][q] + statsS[3][q];
    float inv = 1.f / lrow;
    float* orow = g_o + ((size_t)(bt * 512) + q0 + q) * 128 + h * 32 + d0;
#pragma unroll
    for (int dd = 0; dd < 4; ++dd) {
        float s = Op[(0 * 32 + q) * 33 + d0 + dd] + Op[(1 * 32 + q) * 33 + d0 + dd]
                + Op[(2 * 32 + q) * 33 + d0 + dd] + Op[(3 * 32 + q) * 33 + d0 + dd];
        orow[dd] = s * inv;
    }
}

// ------- K_fin1: attn out_proj GEMM + residual + LayerNorm -> g_zo (transposed) -------
// LDS: At[32][132] @0 (16896 B), Bs[32][128] @16896 (16384 B) during K loop;
//      X[128][133] @0 (68096 B) overlays both after last sync.
#define FIN1_LDS 68096
__global__ __launch_bounds__(256, 1) void k_fin1(const float* __restrict__ bo,
                       const float* __restrict__ ln_w, const float* __restrict__ ln_b) {
    extern __shared__ char smem[];
    float* At = (float*)smem;                     // [32][132]
    float* Bs = (float*)(smem + 16896);           // [32][128]
    float* X  = (float*)smem;                     // [128][133] overlay
    __shared__ float mu_s[128], rs_s[128];
    int blk = blockIdx.x;                         // 256 = 64 bt * 4 qt
    int qt = blk & 3, bt = blk >> 2;
    int row0 = bt * 512 + qt * 128;
    int tid = threadIdx.x;
    int mi = tid & 15;
    int ni = tid >> 4;

    float4 acc[2][2][4];
#pragma unroll
    for (int a = 0; a < 2; ++a)
#pragma unroll
        for (int bq = 0; bq < 2; ++bq)
#pragma unroll
            for (int rr = 0; rr < 4; ++rr)
                acc[a][bq][rr] = make_float4(0.f, 0.f, 0.f, 0.f);

    for (int kc = 0; kc < 128; kc += 32) {
#pragma unroll
        for (int i = 0; i < 16; ++i) {
            int e = tid + i * 256;
            int m = e >> 5, cs = e & 31;
            At[cs * 132 + m] = g_o[(size_t)(row0 + m) * 128 + kc + cs];
        }
#pragma unroll
        for (int i = 0; i < 16; ++i) {
            int e = tid + i * 256;
            int cs = e >> 7, n = e & 127;
            Bs[cs * 128 + n] = g_wot[(kc + cs) * 128 + n];
        }
        __syncthreads();
#pragma unroll 8
        for (int c = 0; c < 32; ++c) {
            float4 a0 = *(const float4*)&At[c * 132 + 4 * mi];
            float4 a1 = *(const float4*)&At[c * 132 + 64 + 4 * mi];
            float4 b0 = *(const float4*)&Bs[c * 128 + 4 * ni];
            float4 b1 = *(const float4*)&Bs[c * 128 + 64 + 4 * ni];
            float ar[8] = {a0.x, a0.y, a0.z, a0.w, a1.x, a1.y, a1.z, a1.w};
#pragma unroll
            for (int r = 0; r < 8; ++r) {
                int a = r >> 2, rr = r & 3;
                acc[a][0][rr].x += ar[r] * b0.x; acc[a][0][rr].y += ar[r] * b0.y;
                acc[a][0][rr].z += ar[r] * b0.z; acc[a][0][rr].w += ar[r] * b0.w;
                acc[a][1][rr].x += ar[r] * b1.x; acc[a][1][rr].y += ar[r] * b1.y;
                acc[a][1][rr].z += ar[r] * b1.z; acc[a][1][rr].w += ar[r] * b1.w;
            }
        }
        __syncthreads();
    }

    // epilogue: xi = acc + bias + g_zs residual -> X tile
#pragma unroll
    for (int a = 0; a < 2; ++a)
#pragma unroll
        for (int rr = 0; rr < 4; ++rr) {
            int r = a * 64 + 4 * mi + rr;         // local token row
#pragma unroll
            for (int bq = 0; bq < 2; ++bq) {
                int col = bq * 64 + 4 * ni;
                float4 z4 = *(const float4*)&g_zs[(size_t)(row0 + r) * 128 + col];
                float4 v = acc[a][bq][rr];
                v.x += bo[col + 0] + z4.x;
                v.y += bo[col + 1] + z4.y;
                v.z += bo[col + 2] + z4.z;
                v.w += bo[col + 3] + z4.w;
                X[r * 133 + col + 0] = v.x;
                X[r * 133 + col + 1] = v.y;
                X[r * 133 + col + 2] = v.z;
                X[r * 133 + col + 3] = v.w;
            }
        }
    __syncthreads();

    if (tid < 128) {                              // per-token LN stats
        float s1 = 0.f, s2 = 0.f;
        for (int j = 0; j < 128; ++j) {
            float v = X[tid * 133 + j];
            s1 += v; s2 += v * v;
        }
        float mu = s1 * (1.f / 128.f);
        float var = s2 * (1.f / 128.f) - mu * mu;
        mu_s[tid] = mu;
        rs_s[tid] = rsqrtf(fmaxf(var, 0.f) + 1e-5f);
    }
    __syncthreads();

    // transposed, coalesced write: g_zo[(bt*128 + c) * 512 + qt*128 + q]
#pragma unroll
    for (int it = 0; it < 64; ++it) {
        int e = tid + it * 256;                   // 16384
        int q = e & 127, cc = e >> 7;
        float val = (X[q * 133 + cc] - mu_s[q]) * rs_s[q] * ln_w[cc] + ln_b[cc];
        g_zo[((size_t)(bt * 128 + cc)) * 512 + qt * 128 + q] = val;
    }
}

// ------- K_fin2: full-row densify: out = x_in + scatter(g_zo); replaces k_copy -------
__global__ __launch_bounds__(256) void k_fin2(const float* __restrict__ x_in,
                                              float* __restrict__ out) {
    __shared__ float dense[1024];
    int R = blockIdx.x;                           // 8192 rows = bt*128 + c
    int bt = R >> 7;
    int b = bt >> 3;
    int tid = threadIdx.x;
#pragma unroll
    for (int i = 0; i < 4; ++i) dense[tid + i * 256] = 0.f;
    __syncthreads();
#pragma unroll
    for (int hh = 0; hh < 2; ++hh) {
        int k = tid + hh * 256;
        int n = g_idx[b * KK + k] & 1023;
        dense[n] = g_zo[(size_t)R * 512 + k];
    }
    __syncthreads();
    const float4* xr = (const float4*)(x_in + (size_t)R * 1024);
    const float4* dn = (const float4*)dense;
    float4* orr = (float4*)(out + (size_t)R * 1024);
    float4 xv = xr[tid], dv = dn[tid];
    float4 ov;
    ov.x = xv.x + dv.x; ov.y = xv.y + dv.y; ov.z = xv.z + dv.z; ov.w = xv.w + dv.w;
    orr[tid] = ov;
}

extern "C" void kernel_launch(void* const* d_in, const int* in_sizes, int n_in,
                              void* d_out, int out_size, void* d_ws, size_t ws_size,
                              hipStream_t stream) {
    const float* x_in      = (const float*)d_in[0];
    const float* norm1_w   = (const float*)d_in[1];
    const float* in_proj_w = (const float*)d_in[2];
    const float* conv1d_w  = (const float*)d_in[3];
    const float* conv1d_b  = (const float*)d_in[4];
    const float* x_proj_w  = (const float*)d_in[5];
    const float* dt_proj_w = (const float*)d_in[6];
    const float* dt_proj_b = (const float*)d_in[7];
    const float* A_log     = (const float*)d_in[8];
    const float* Dp        = (const float*)d_in[9];
    const float* out_proj_w= (const float*)d_in[10];
    const float* r1_w      = (const float*)d_in[11];
    const float* r1_b      = (const float*)d_in[12];
    const float* r2_w      = (const float*)d_in[13];
    const float* r2_b      = (const float*)d_in[14];
    const float* attn_in_w = (const float*)d_in[15];
    const float* attn_in_b = (const float*)d_in[16];
    const float* attn_out_w= (const float*)d_in[17];
    const float* attn_out_b= (const float*)d_in[18];
    const float* ln_w      = (const float*)d_in[19];
    const float* ln_b      = (const float*)d_in[20];
    // d_in[21]: current_epoch == 20 (static) -> ratio 0.5 -> K = 512

    float* out = (float*)d_out;

    static bool attr_set = false;
    if (!attr_set) {
        hipFuncSetAttribute(reinterpret_cast<const void*>(k_attn3),
                            hipFuncAttributeMaxDynamicSharedMemorySize, ATTN_LDS);
        hipFuncSetAttribute(reinterpret_cast<const void*>(k_fin1),
                            hipFuncAttributeMaxDynamicSharedMemorySize, FIN1_LDS);
        attr_set = true;
    }

    t_init<<<16, 256, 0, stream>>>(0);
    k_mean<<<4096, 256, 0, stream>>>(x_in);
    k_router_conv<<<1024, 256, 0, stream>>>(r1_w, r1_b);
    k_topk<<<8, 1024, 0, stream>>>(r2_w, r2_b);
    k_gather<<<512, 256, 0, stream>>>(x_in);
    k_wt<<<256, 256, 0, stream>>>(in_proj_w, out_proj_w, attn_out_w);
    k_rms<<<8192, 256, 0, stream>>>(norm1_w);
    k_gemm<128, 512, 0><<<1024, 256, 0, stream>>>();   // in_proj
    k_scan<<<4096, 256, 0, stream>>>(x_proj_w, conv1d_w, conv1d_b,
                                     dt_proj_w, dt_proj_b, A_log, Dp);
    k_gemm<256, 128, 1><<<256, 256, 0, stream>>>();    // out_proj (+ layout scatter)
    k_qkv<<<1024, 256, 0, stream>>>(attn_in_w, attn_in_b);
    k_attn3<<<1024, 256, ATTN_LDS, stream>>>();
    k_fin1<<<256, 256, FIN1_LDS, stream>>>(attn_out_b, ln_w, ln_b);
    k_fin2<<<8192, 256, 0, stream>>>(x_in, out);
}